// Round 4
// baseline (109.610 us; speedup 1.0000x reference)
//
#include <hip/hip_runtime.h>
#include <cstdint>

#define NN 1024      // nodes
#define NE 16384     // edges
#define DF 256       // features
#define UB 2.0f      // upper bound
#define MAXSEL 6
#define CAP 128      // slot capacity per node (max degree ~40 for this input)

typedef unsigned long long u64;

// ---- K1: fused per-edge L2 distance + slotted CSR + ADJ bits + min/max ----
// 4 edges per block (one wave each). f64 accumulation of f32-rounded diffs.
// Slot key packs (distbits:32 | edge_id:14 | dst:10): u64 ordering == ordering
// by (dist, edge_id), which equals ordering by (score, edge_id) since the
// score map is monotone affine. Tie-break = first edge id, like jnp.argmin.
__global__ void k_dist_build(const float* __restrict__ x, const int* __restrict__ src,
                             const int* __restrict__ dst, int* __restrict__ deg,
                             u64* __restrict__ slots, uint32_t* __restrict__ ADJ,
                             uint32_t* __restrict__ bmin, uint32_t* __restrict__ bmax) {
    int wid = threadIdx.x >> 6;
    int lane = threadIdx.x & 63;
    int e = blockIdx.x * 4 + wid;
    int u = src[e], v = dst[e];
    float4 a = ((const float4*)(x + (size_t)u * DF))[lane];
    float4 b = ((const float4*)(x + (size_t)v * DF))[lane];
    float d0 = a.x - b.x, d1 = a.y - b.y, d2 = a.z - b.z, d3 = a.w - b.w;
    double s = (double)d0 * d0 + (double)d1 * d1 + (double)d2 * d2 + (double)d3 * d3;
    for (int off = 32; off; off >>= 1) s += __shfl_xor(s, off, 64);
    if (lane == 0) {
        float dist = sqrtf((float)s);
        uint32_t db = __float_as_uint(dist);         // dist >= 0 -> bits monotone
        int pos = atomicAdd(&deg[u], 1);
        if (pos < CAP)
            slots[(size_t)u * CAP + pos] =
                ((u64)db << 24) | ((u64)(uint32_t)e << 10) | (u64)(uint32_t)v;
        atomicOr(&ADJ[(size_t)u * 32 + (v >> 5)], 1u << (v & 31));
        int bkt = (blockIdx.x * 4 + wid) & 63;       // spread atomics over 64 buckets
        atomicMax(&bmin[bkt], ~db);                  // min via max of ~bits (0-init ok)
        atomicMax(&bmax[bkt], db);
    }
}

// ---- K2: greedy cluster search, 1 wave per seed; also zeroes maskT ----
__global__ void k_search(const int* __restrict__ deg, const u64* __restrict__ slots,
                         const uint32_t* __restrict__ bmin, const uint32_t* __restrict__ bmax,
                         const int* __restrict__ src,
                         uint32_t* __restrict__ masks, uint32_t* __restrict__ maskT,
                         int* __restrict__ selU, int* __restrict__ selV,
                         float* __restrict__ selS, int* __restrict__ selCnt,
                         u64* __restrict__ sig) {
    __shared__ uint32_t inc[32];
    __shared__ int members[8];
    __shared__ float s_tot;
    __shared__ int s_nmem;
    int i = blockIdx.x, lane = threadIdx.x;
    if (lane < 32) { maskT[(size_t)i * 32 + lane] = 0; inc[lane] = 0; }

    // reduce 64 min/max buckets -> MN, MX (all lanes)
    uint32_t am = bmin[lane], bx = bmax[lane];
    for (int off = 32; off; off >>= 1) {
        uint32_t oa = (uint32_t)__shfl_xor((int)am, off, 64);
        uint32_t ob = (uint32_t)__shfl_xor((int)bx, off, 64);
        am = am > oa ? am : oa;
        bx = bx > ob ? bx : ob;
    }
    float MN = __uint_as_float(~am);
    float MX = __uint_as_float(bx);

    if (lane == 0) {
        inc[i >> 5] = 1u << (i & 31);
        members[0] = i;
        s_tot = 0.0f;
        s_nmem = 1;
    }
    __syncthreads();
    int cnt = 0;
    for (int step = 0; step < MAXSEL; ++step) {
        if (s_tot >= UB) break;                      // uniform LDS scalar
        u64 best = ~0ull;
        int nm = s_nmem;
        for (int m = 0; m < nm; ++m) {
            int u = members[m];
            int dc = deg[u];
            if (dc > CAP) dc = CAP;
            const u64* sl = slots + (size_t)u * CAP;
            for (int k = lane; k < dc; k += 64) {
                u64 t = sl[k];
                int v = (int)(t & 1023);
                if (!((inc[v >> 5] >> (v & 31)) & 1u) && t < best) best = t;
            }
        }
        for (int off = 32; off; off >>= 1) {
            u64 o = __shfl_xor(best, off, 64);
            if (o < best) best = o;
        }
        if (best == ~0ull) break;                    // no frontier edge
        if (lane == 0) {
            uint32_t db = (uint32_t)(best >> 24);
            int e = (int)((best >> 10) & 0x3FFF);
            int v = (int)(best & 1023);
            float dd = __uint_as_float(db);
            float s = (dd - MN) / (MX - MN) + 0.5f;  // exact reference f32 ops
            int u = src[e];
            inc[v >> 5] |= 1u << (v & 31);
            members[s_nmem++] = v;
            selU[i * 8 + cnt] = u;
            selV[i * 8 + cnt] = v;
            selS[i * 8 + cnt] = s;
            s_tot += s;                              // f32, same order as reference
        }
        cnt++;
        __syncthreads();
    }
    if (lane == 0) {
        selCnt[i] = cnt;
        u64 h = 1469598103934665603ull;
        for (int w = 0; w < 32; ++w) { h ^= inc[w]; h *= 1099511628211ull; }
        sig[i] = h;
    }
    if (lane < 32) masks[(size_t)i * 32 + lane] = inc[lane];
}

// ---- K3: dedup (parallel) + scatter kept-cluster bits into maskT ----
// maskT[n] = 1024-bit vector over clusters j: bit j set iff keep[j] && n in cluster j
__global__ void k_dedup(const uint32_t* __restrict__ masks,
                        const u64* __restrict__ sig,
                        const int* __restrict__ selV, const int* __restrict__ selCnt,
                        int* __restrict__ keep, uint32_t* __restrict__ maskT) {
    __shared__ int s_dup;
    int i = blockIdx.x, t = threadIdx.x;
    if (t == 0) s_dup = 0;
    __syncthreads();
    u64 h = sig[i];
    int dup = 0;
    for (int j = t; j < i; j += 256) {
        if (sig[j] == h) {
            const uint32_t* mi = masks + (size_t)i * 32;
            const uint32_t* mj = masks + (size_t)j * 32;
            bool eq = true;
            for (int w = 0; w < 32 && eq; ++w) eq = (mi[w] == mj[w]);
            if (eq) dup = 1;
        }
    }
    if (__any(dup)) { if ((t & 63) == 0) s_dup = 1; }
    __syncthreads();
    int kp = !s_dup;
    if (t == 0) keep[i] = kp;
    if (kp) {
        int wrd = i >> 5;
        uint32_t bit = 1u << (i & 31);
        if (t == 0) atomicOr(&maskT[(size_t)i * 32 + wrd], bit);      // self
        int c = selCnt[i];
        if (t >= 1 && t <= c) {
            int v = selV[i * 8 + (t - 1)];
            atomicOr(&maskT[(size_t)v * 32 + wrd], bit);
        }
    }
}

// ---- K4: all four outputs, one block per row i ----
__global__ void k_rows(const float* __restrict__ x, const uint32_t* __restrict__ ADJ,
                       const uint32_t* __restrict__ masks, const uint32_t* __restrict__ maskT,
                       const int* __restrict__ keep, const int* __restrict__ selU,
                       const int* __restrict__ selV, const float* __restrict__ selS,
                       const int* __restrict__ selCnt,
                       float* __restrict__ outAdj, float* __restrict__ outAs,
                       float* __restrict__ outNsm, float* __restrict__ outX) {
    __shared__ uint32_t R[32];        // nodes reachable by 1 edge from cluster i
    __shared__ uint32_t MI[32];       // cluster-i membership bits
    __shared__ uint32_t part[8][32];
    __shared__ uint32_t orow[32];     // adj_new row i as bits over j
    __shared__ int su[8], sv[8];
    __shared__ float ss[8];
    __shared__ int s_c;
    int i = blockIdx.x, t = threadIdx.x;
    int kp = keep[i];
    if (t == 0) s_c = selCnt[i];
    if (t < 8) { su[t] = selU[i*8+t]; sv[t] = selV[i*8+t]; ss[t] = selS[i*8+t]; }
    __syncthreads();
    int c = s_c;
    if (t < 32) {
        uint32_t r = ADJ[(size_t)i * 32 + t];
        for (int k = 0; k < c; ++k) r |= ADJ[(size_t)sv[k] * 32 + t];
        R[t] = r;
        MI[t] = masks[(size_t)i * 32 + t];
    }
    __syncthreads();
    // orow = OR over set bits n of R of maskT[n]   (8 groups x 32 lanes)
    int g = t >> 5, l = t & 31;
    uint32_t acc = 0;
    if (kp) {
        for (int wi = g; wi < 32; wi += 8) {
            uint32_t bits = R[wi];
            while (bits) {
                int b = __ffs(bits) - 1;
                bits &= bits - 1;
                acc |= maskT[((size_t)(wi * 32 + b)) * 32 + l];   // coalesced over l
            }
        }
    }
    part[g][l] = acc;
    __syncthreads();
    if (t < 32) {
        uint32_t o = 0;
        for (int gg = 0; gg < 8; ++gg) o |= part[gg][t];
        orow[t] = o;
    }
    __syncthreads();

    // ---- writes: thread t owns j0 = 4t .. 4t+3 (float4, fully coalesced) ----
    int j0 = t * 4;
    int w = j0 >> 5, sh = j0 & 31;
    float4 vadj = {0,0,0,0}, vas = {0,0,0,0}, vnsm = {0,0,0,0};
    if (kp) {
        uint32_t ob = orow[w] >> sh;
        uint32_t mb = MI[w] >> sh;
        vadj.x = ((ob     ) & 1) && (j0     != i) ? 1.0f : 0.0f;
        vadj.y = ((ob >> 1) & 1) && (j0 + 1 != i) ? 1.0f : 0.0f;
        vadj.z = ((ob >> 2) & 1) && (j0 + 2 != i) ? 1.0f : 0.0f;
        vadj.w = ((ob >> 3) & 1) && (j0 + 3 != i) ? 1.0f : 0.0f;
        vas.x = (mb      & 1) ? 1.0f : 0.0f;
        vas.y = ((mb>>1) & 1) ? 1.0f : 0.0f;
        vas.z = ((mb>>2) & 1) ? 1.0f : 0.0f;
        vas.w = ((mb>>3) & 1) ? 1.0f : 0.0f;
        for (int k = 0; k < c; ++k) {
            float h = ss[k] * 0.5f;
            int u = su[k], v = sv[k];
            vnsm.x += ((u == j0    ) ? h : 0.0f) + ((v == j0    ) ? h : 0.0f);
            vnsm.y += ((u == j0 + 1) ? h : 0.0f) + ((v == j0 + 1) ? h : 0.0f);
            vnsm.z += ((u == j0 + 2) ? h : 0.0f) + ((v == j0 + 2) ? h : 0.0f);
            vnsm.w += ((u == j0 + 3) ? h : 0.0f) + ((v == j0 + 3) ? h : 0.0f);
        }
    }
    ((float4*)outAdj)[(size_t)i * (NN/4) + t] = vadj;
    ((float4*)outAs )[(size_t)i * (NN/4) + t] = vas;
    ((float4*)outNsm)[(size_t)i * (NN/4) + t] = vnsm;

    // ---- x_new row i: thread t = feature dim ----
    float accx = 0.0f;
    if (kp) {
        for (int k = 0; k < c; ++k) {
            float h = ss[k] * 0.5f;
            accx += h * x[(size_t)su[k] * DF + t];
            accx += h * x[(size_t)sv[k] * DF + t];
        }
    }
    outX[(size_t)i * DF + t] = accx;
}

extern "C" void kernel_launch(void* const* d_in, const int* in_sizes, int n_in,
                              void* d_out, int out_size, void* d_ws, size_t ws_size,
                              hipStream_t stream) {
    const float* x = (const float*)d_in[0];
    const int* ei = (const int*)d_in[1];
    const int* src = ei;
    const int* dst = ei + NE;

    float* out = (float*)d_out;
    float* out_adj = out;                                  // N*N
    float* out_x   = out + (size_t)NN * NN;                // N*D
    float* out_as  = out_x + (size_t)NN * DF;              // N*N
    float* out_nsm = out_as + (size_t)NN * NN;             // N*N

    char* w = (char*)d_ws;
    u64*      slots = (u64*)w;       w += (size_t)NN * CAP * 8;   // 8B-aligned first
    u64*      sig   = (u64*)w;       w += (size_t)NN * 8;
    // ---- zeroed region (contiguous): deg, ADJ, bmin, bmax ----
    int*      deg   = (int*)w;       w += (size_t)NN * 4;
    uint32_t* ADJ   = (uint32_t*)w;  w += (size_t)NN * 32 * 4;
    uint32_t* bmin  = (uint32_t*)w;  w += 64 * 4;
    uint32_t* bmax  = (uint32_t*)w;  w += 64 * 4;
    // ---- end zeroed region (maskT is zeroed by k_search) ----
    uint32_t* maskT = (uint32_t*)w;  w += (size_t)NN * 32 * 4;
    uint32_t* masks = (uint32_t*)w;  w += (size_t)NN * 32 * 4;
    int*      selU  = (int*)w;       w += (size_t)NN * 8 * 4;
    int*      selV  = (int*)w;       w += (size_t)NN * 8 * 4;
    float*    selS  = (float*)w;     w += (size_t)NN * 8 * 4;
    int*      selCnt= (int*)w;       w += (size_t)NN * 4;
    int*      keep  = (int*)w;       w += (size_t)NN * 4;

    hipMemsetAsync(deg, 0, (size_t)NN * 4 + (size_t)NN * 32 * 4 + 128 * 4, stream);

    k_dist_build<<<NE / 4, 256, 0, stream>>>(x, src, dst, deg, slots, ADJ, bmin, bmax);
    k_search<<<NN, 64, 0, stream>>>(deg, slots, bmin, bmax, src,
                                    masks, maskT, selU, selV, selS, selCnt, sig);
    k_dedup<<<NN, 256, 0, stream>>>(masks, sig, selV, selCnt, keep, maskT);
    k_rows<<<NN, 256, 0, stream>>>(x, ADJ, masks, maskT, keep, selU, selV, selS, selCnt,
                                   out_adj, out_as, out_nsm, out_x);
}

// Round 5
// 42.459 us; speedup vs baseline: 2.5815x; 2.5815x over previous
//
#include <hip/hip_runtime.h>
#include <cstdint>

#define NN 1024      // nodes
#define NE 16384     // edges
#define DF 256       // features
#define UB 2.0f      // upper bound
#define MAXSEL 6
#define CAP 128      // slot capacity per node (max degree ~40 for this input)
#define NB (NE/4)    // k_dist_build blocks

typedef unsigned long long u64;

// ---- K1: fused per-edge L2 distance + slotted CSR + ADJ bits + block min/max ----
// 4 edges per block (one wave each). f64 accumulation of f32-rounded diffs.
// Slot key packs (distbits:32 | edge_id:14 | dst:10): u64 ordering == ordering
// by (dist, edge_id) == ordering by (score, edge_id) since score is a monotone
// affine map of dist. Tie-break = first edge id, like jnp.argmin.
// Min/max: per-block LDS reduce + plain store (NO narrow atomics — round-4's
// 81us was 32K atomicMax serialized on 8 cache lines).
__global__ void k_dist_build(const float* __restrict__ x, const int* __restrict__ src,
                             const int* __restrict__ dst, int* __restrict__ deg,
                             u64* __restrict__ slots, uint32_t* __restrict__ ADJ,
                             uint32_t* __restrict__ pmin, uint32_t* __restrict__ pmax) {
    __shared__ uint32_t smin[4], smax[4];
    int wid = threadIdx.x >> 6;
    int lane = threadIdx.x & 63;
    int e = blockIdx.x * 4 + wid;
    int u = src[e], v = dst[e];
    float4 a = ((const float4*)(x + (size_t)u * DF))[lane];
    float4 b = ((const float4*)(x + (size_t)v * DF))[lane];
    float d0 = a.x - b.x, d1 = a.y - b.y, d2 = a.z - b.z, d3 = a.w - b.w;
    double s = (double)d0 * d0 + (double)d1 * d1 + (double)d2 * d2 + (double)d3 * d3;
    for (int off = 32; off; off >>= 1) s += __shfl_xor(s, off, 64);
    if (lane == 0) {
        float dist = sqrtf((float)s);
        uint32_t db = __float_as_uint(dist);         // dist >= 0 -> bits monotone
        int pos = atomicAdd(&deg[u], 1);
        if (pos < CAP)
            slots[(size_t)u * CAP + pos] =
                ((u64)db << 24) | ((u64)(uint32_t)e << 10) | (u64)(uint32_t)v;
        atomicOr(&ADJ[(size_t)u * 32 + (v >> 5)], 1u << (v & 31));
        smin[wid] = db;
        smax[wid] = db;
    }
    __syncthreads();
    if (threadIdx.x == 0) {
        uint32_t mn = min(min(smin[0], smin[1]), min(smin[2], smin[3]));
        uint32_t mx = max(max(smax[0], smax[1]), max(smax[2], smax[3]));
        pmin[blockIdx.x] = mn;
        pmax[blockIdx.x] = mx;
    }
}

// ---- K2: greedy cluster search, 1 wave per seed; also zeroes maskT ----
__global__ void k_search(const int* __restrict__ deg, const u64* __restrict__ slots,
                         const uint32_t* __restrict__ pmin, const uint32_t* __restrict__ pmax,
                         const int* __restrict__ src,
                         uint32_t* __restrict__ masks, uint32_t* __restrict__ maskT,
                         int* __restrict__ selU, int* __restrict__ selV,
                         float* __restrict__ selS, int* __restrict__ selCnt,
                         u64* __restrict__ sig) {
    __shared__ uint32_t inc[32];
    __shared__ int members[8];
    __shared__ float s_tot;
    __shared__ int s_nmem;
    int i = blockIdx.x, lane = threadIdx.x;
    if (lane < 32) { maskT[(size_t)i * 32 + lane] = 0; inc[lane] = 0; }

    // reduce 4096 block partials -> MN, MX (uint4 loads, 16 iters/lane)
    uint32_t mnb = 0xFFFFFFFFu, mxb = 0u;
    const uint4* p4n = (const uint4*)pmin;
    const uint4* p4x = (const uint4*)pmax;
    for (int k = lane; k < NB / 4; k += 64) {
        uint4 a = p4n[k], b = p4x[k];
        mnb = min(mnb, min(min(a.x, a.y), min(a.z, a.w)));
        mxb = max(mxb, max(max(b.x, b.y), max(b.z, b.w)));
    }
    for (int off = 32; off; off >>= 1) {
        uint32_t oa = (uint32_t)__shfl_xor((int)mnb, off, 64);
        uint32_t ob = (uint32_t)__shfl_xor((int)mxb, off, 64);
        mnb = min(mnb, oa);
        mxb = max(mxb, ob);
    }
    float MN = __uint_as_float(mnb);
    float MX = __uint_as_float(mxb);

    if (lane == 0) {
        inc[i >> 5] = 1u << (i & 31);
        members[0] = i;
        s_tot = 0.0f;
        s_nmem = 1;
    }
    __syncthreads();
    int cnt = 0;
    for (int step = 0; step < MAXSEL; ++step) {
        if (s_tot >= UB) break;                      // uniform LDS scalar
        u64 best = ~0ull;
        int nm = s_nmem;
        for (int m = 0; m < nm; ++m) {
            int u = members[m];
            int dc = deg[u];
            if (dc > CAP) dc = CAP;
            const u64* sl = slots + (size_t)u * CAP;
            for (int k = lane; k < dc; k += 64) {
                u64 t = sl[k];
                int v = (int)(t & 1023);
                if (!((inc[v >> 5] >> (v & 31)) & 1u) && t < best) best = t;
            }
        }
        for (int off = 32; off; off >>= 1) {
            u64 o = __shfl_xor(best, off, 64);
            if (o < best) best = o;
        }
        if (best == ~0ull) break;                    // no frontier edge
        if (lane == 0) {
            uint32_t db = (uint32_t)(best >> 24);
            int e = (int)((best >> 10) & 0x3FFF);
            int v = (int)(best & 1023);
            float dd = __uint_as_float(db);
            float s = (dd - MN) / (MX - MN) + 0.5f;  // exact reference f32 ops
            int u = src[e];
            inc[v >> 5] |= 1u << (v & 31);
            members[s_nmem++] = v;
            selU[i * 8 + cnt] = u;
            selV[i * 8 + cnt] = v;
            selS[i * 8 + cnt] = s;
            s_tot += s;                              // f32, same order as reference
        }
        cnt++;
        __syncthreads();
    }
    if (lane == 0) {
        selCnt[i] = cnt;
        u64 h = 1469598103934665603ull;
        for (int w = 0; w < 32; ++w) { h ^= inc[w]; h *= 1099511628211ull; }
        sig[i] = h;
    }
    if (lane < 32) masks[(size_t)i * 32 + lane] = inc[lane];
}

// ---- K3: dedup (parallel) + scatter kept-cluster bits into maskT ----
// maskT[n] = 1024-bit vector over clusters j: bit j set iff keep[j] && n in cluster j
__global__ void k_dedup(const uint32_t* __restrict__ masks,
                        const u64* __restrict__ sig,
                        const int* __restrict__ selV, const int* __restrict__ selCnt,
                        int* __restrict__ keep, uint32_t* __restrict__ maskT) {
    __shared__ int s_dup;
    int i = blockIdx.x, t = threadIdx.x;
    if (t == 0) s_dup = 0;
    __syncthreads();
    u64 h = sig[i];
    int dup = 0;
    for (int j = t; j < i; j += 256) {
        if (sig[j] == h) {
            const uint32_t* mi = masks + (size_t)i * 32;
            const uint32_t* mj = masks + (size_t)j * 32;
            bool eq = true;
            for (int w = 0; w < 32 && eq; ++w) eq = (mi[w] == mj[w]);
            if (eq) dup = 1;
        }
    }
    if (__any(dup)) { if ((t & 63) == 0) s_dup = 1; }
    __syncthreads();
    int kp = !s_dup;
    if (t == 0) keep[i] = kp;
    if (kp) {
        int wrd = i >> 5;
        uint32_t bit = 1u << (i & 31);
        if (t == 0) atomicOr(&maskT[(size_t)i * 32 + wrd], bit);      // self
        int c = selCnt[i];
        if (t >= 1 && t <= c) {
            int v = selV[i * 8 + (t - 1)];
            atomicOr(&maskT[(size_t)v * 32 + wrd], bit);
        }
    }
}

// ---- K4: all four outputs, one block per row i ----
__global__ void k_rows(const float* __restrict__ x, const uint32_t* __restrict__ ADJ,
                       const uint32_t* __restrict__ masks, const uint32_t* __restrict__ maskT,
                       const int* __restrict__ keep, const int* __restrict__ selU,
                       const int* __restrict__ selV, const float* __restrict__ selS,
                       const int* __restrict__ selCnt,
                       float* __restrict__ outAdj, float* __restrict__ outAs,
                       float* __restrict__ outNsm, float* __restrict__ outX) {
    __shared__ uint32_t R[32];        // nodes reachable by 1 edge from cluster i
    __shared__ uint32_t MI[32];       // cluster-i membership bits
    __shared__ uint32_t part[8][32];
    __shared__ uint32_t orow[32];     // adj_new row i as bits over j
    __shared__ int su[8], sv[8];
    __shared__ float ss[8];
    __shared__ int s_c;
    int i = blockIdx.x, t = threadIdx.x;
    int kp = keep[i];
    if (t == 0) s_c = selCnt[i];
    if (t < 8) { su[t] = selU[i*8+t]; sv[t] = selV[i*8+t]; ss[t] = selS[i*8+t]; }
    __syncthreads();
    int c = s_c;
    if (t < 32) {
        uint32_t r = ADJ[(size_t)i * 32 + t];
        for (int k = 0; k < c; ++k) r |= ADJ[(size_t)sv[k] * 32 + t];
        R[t] = r;
        MI[t] = masks[(size_t)i * 32 + t];
    }
    __syncthreads();
    // orow = OR over set bits n of R of maskT[n]   (8 groups x 32 lanes)
    int g = t >> 5, l = t & 31;
    uint32_t acc = 0;
    if (kp) {
        for (int wi = g; wi < 32; wi += 8) {
            uint32_t bits = R[wi];
            while (bits) {
                int b = __ffs(bits) - 1;
                bits &= bits - 1;
                acc |= maskT[((size_t)(wi * 32 + b)) * 32 + l];   // coalesced over l
            }
        }
    }
    part[g][l] = acc;
    __syncthreads();
    if (t < 32) {
        uint32_t o = 0;
        for (int gg = 0; gg < 8; ++gg) o |= part[gg][t];
        orow[t] = o;
    }
    __syncthreads();

    // ---- writes: thread t owns j0 = 4t .. 4t+3 (float4, fully coalesced) ----
    int j0 = t * 4;
    int w = j0 >> 5, sh = j0 & 31;
    float4 vadj = {0,0,0,0}, vas = {0,0,0,0}, vnsm = {0,0,0,0};
    if (kp) {
        uint32_t ob = orow[w] >> sh;
        uint32_t mb = MI[w] >> sh;
        vadj.x = ((ob     ) & 1) && (j0     != i) ? 1.0f : 0.0f;
        vadj.y = ((ob >> 1) & 1) && (j0 + 1 != i) ? 1.0f : 0.0f;
        vadj.z = ((ob >> 2) & 1) && (j0 + 2 != i) ? 1.0f : 0.0f;
        vadj.w = ((ob >> 3) & 1) && (j0 + 3 != i) ? 1.0f : 0.0f;
        vas.x = (mb      & 1) ? 1.0f : 0.0f;
        vas.y = ((mb>>1) & 1) ? 1.0f : 0.0f;
        vas.z = ((mb>>2) & 1) ? 1.0f : 0.0f;
        vas.w = ((mb>>3) & 1) ? 1.0f : 0.0f;
        for (int k = 0; k < c; ++k) {
            float h = ss[k] * 0.5f;
            int u = su[k], v = sv[k];
            vnsm.x += ((u == j0    ) ? h : 0.0f) + ((v == j0    ) ? h : 0.0f);
            vnsm.y += ((u == j0 + 1) ? h : 0.0f) + ((v == j0 + 1) ? h : 0.0f);
            vnsm.z += ((u == j0 + 2) ? h : 0.0f) + ((v == j0 + 2) ? h : 0.0f);
            vnsm.w += ((u == j0 + 3) ? h : 0.0f) + ((v == j0 + 3) ? h : 0.0f);
        }
    }
    ((float4*)outAdj)[(size_t)i * (NN/4) + t] = vadj;
    ((float4*)outAs )[(size_t)i * (NN/4) + t] = vas;
    ((float4*)outNsm)[(size_t)i * (NN/4) + t] = vnsm;

    // ---- x_new row i: thread t = feature dim ----
    float accx = 0.0f;
    if (kp) {
        for (int k = 0; k < c; ++k) {
            float h = ss[k] * 0.5f;
            accx += h * x[(size_t)su[k] * DF + t];
            accx += h * x[(size_t)sv[k] * DF + t];
        }
    }
    outX[(size_t)i * DF + t] = accx;
}

extern "C" void kernel_launch(void* const* d_in, const int* in_sizes, int n_in,
                              void* d_out, int out_size, void* d_ws, size_t ws_size,
                              hipStream_t stream) {
    const float* x = (const float*)d_in[0];
    const int* ei = (const int*)d_in[1];
    const int* src = ei;
    const int* dst = ei + NE;

    float* out = (float*)d_out;
    float* out_adj = out;                                  // N*N
    float* out_x   = out + (size_t)NN * NN;                // N*D
    float* out_as  = out_x + (size_t)NN * DF;              // N*N
    float* out_nsm = out_as + (size_t)NN * NN;             // N*N

    char* w = (char*)d_ws;
    u64*      slots = (u64*)w;       w += (size_t)NN * CAP * 8;   // 8B-aligned first
    u64*      sig   = (u64*)w;       w += (size_t)NN * 8;
    // ---- zeroed region (contiguous): deg, ADJ ----
    int*      deg   = (int*)w;       w += (size_t)NN * 4;
    uint32_t* ADJ   = (uint32_t*)w;  w += (size_t)NN * 32 * 4;
    // ---- end zeroed region (maskT is zeroed by k_search; pmin/pmax fully written) ----
    uint32_t* pmin  = (uint32_t*)w;  w += (size_t)NB * 4;
    uint32_t* pmax  = (uint32_t*)w;  w += (size_t)NB * 4;
    uint32_t* maskT = (uint32_t*)w;  w += (size_t)NN * 32 * 4;
    uint32_t* masks = (uint32_t*)w;  w += (size_t)NN * 32 * 4;
    int*      selU  = (int*)w;       w += (size_t)NN * 8 * 4;
    int*      selV  = (int*)w;       w += (size_t)NN * 8 * 4;
    float*    selS  = (float*)w;     w += (size_t)NN * 8 * 4;
    int*      selCnt= (int*)w;       w += (size_t)NN * 4;
    int*      keep  = (int*)w;       w += (size_t)NN * 4;

    hipMemsetAsync(deg, 0, (size_t)NN * 4 + (size_t)NN * 32 * 4, stream);

    k_dist_build<<<NB, 256, 0, stream>>>(x, src, dst, deg, slots, ADJ, pmin, pmax);
    k_search<<<NN, 64, 0, stream>>>(deg, slots, pmin, pmax, src,
                                    masks, maskT, selU, selV, selS, selCnt, sig);
    k_dedup<<<NN, 256, 0, stream>>>(masks, sig, selV, selCnt, keep, maskT);
    k_rows<<<NN, 256, 0, stream>>>(x, ADJ, masks, maskT, keep, selU, selV, selS, selCnt,
                                   out_adj, out_as, out_nsm, out_x);
}